// Round 12
// baseline (154.967 us; speedup 1.0000x reference)
//
#include <hip/hip_runtime.h>
#include <math.h>

#define NSITES 131072      // 32*16*16*16
#define PL     (NSITES * 9)   // floats per feature plane

struct cplx { float re, im; };

__device__ __forceinline__ cplx cadd(cplx a, cplx b) { return {a.re + b.re, a.im + b.im}; }
__device__ __forceinline__ cplx cmul(cplx a, cplx b) {
    return { fmaf(a.re, b.re, -(a.im * b.im)), fmaf(a.re, b.im, a.im * b.re) };
}

// 12-byte vector load (global_load_dwordx3); rows are 36 B so only 4B-aligned
struct __attribute__((aligned(4))) f3 { float x, y, z; };
__device__ __forceinline__ f3 ld3(const float* __restrict__ p) { return *(const f3*)p; }

// Named-field structs, everything BY VALUE (R9 pointer-array and R10
// by-reference both stack-demoted -> 27-45 MB scratch; R11 by-value = clean).
struct Acc9 { float r01, r02, r12, i01, i02, i12, d0, d4, d8; };
struct Edof { float er01, er02, er12, ei01, ei02, ei12, ed0, ed1, ed2; };
struct G3   { cplx g0, g1, g2; };
struct C3   { cplx c0, c1, c2; };

__device__ __forceinline__ Edof make_edof(Acc9 a) {
    Edof E;
    E.er01 = a.r01; E.er02 = a.r02; E.er12 = a.r12;
    E.ei01 = a.i01; E.ei02 = a.i02; E.ei12 = a.i12;
    float t3 = (a.d0 + a.d4 + a.d8) * (2.f / 3.f);
    E.ed0 = fmaf(2.f, a.d0, -t3);
    E.ed1 = fmaf(2.f, a.d4, -t3);
    E.ed2 = fmaf(2.f, a.d8, -t3);     // == -ed0-ed1
    return E;
}

// exp(E) = g0 I + g1 E + g2 E^2 via Cayley-Hamilton (p real, q imaginary),
// scaling from exponent bits of ||E||_F^2, Taylor(10) + repeated squaring.
__device__ __forceinline__ G3 expm_coeffs(Edof E)
{
    float r2 = fmaf(E.er01, E.er01, fmaf(E.er02, E.er02, fmaf(E.er12, E.er12,
               fmaf(E.ei01, E.ei01, fmaf(E.ei02, E.ei02, E.ei12 * E.ei12)))));
    r2 = fmaf(2.f, r2, fmaf(E.ed0, E.ed0, fmaf(E.ed1, E.ed1, E.ed2 * E.ed2)));

    const float n01 = fmaf(E.ei01, E.ei01, E.er01 * E.er01);
    const float n02 = fmaf(E.ei02, E.ei02, E.er02 * E.er02);
    const float n12 = fmaf(E.ei12, E.ei12, E.er12 * E.er12);
    const float zre = fmaf(E.ei01, E.ei12, -(E.er01 * E.er12));
    const float zim = -fmaf(E.ei01, E.er12, E.er01 * E.ei12);
    const float detH = E.ed0 * E.ed1 * E.ed2
                     + 2.f * fmaf(zre, E.ei02, -(zim * E.er02))
                     - fmaf(E.ed0, n12, fmaf(E.ed1, n02, E.ed2 * n01));

    int e; (void)frexpf(r2, &e);                 // r2 = m*2^e, m in [0.5,1)
    int sc = (e <= -2) ? 0 : min(1 + ((e + 1) >> 1), 40);
    const float inv  = __int_as_float((127 - sc) << 23);   // 2^-sc
    const float inv2 = inv * inv;
    const float px   = -0.5f * r2 * inv2;        // p of scaled X (real)
    const float qxi  = -detH * (inv2 * inv);     // q of scaled X = i*qxi

    cplx T0 = {1.f, 0.f}, T1 = {0.f, 0.f}, T2 = {0.f, 0.f};
    cplx S0 = {1.f, 0.f}, S1 = {0.f, 0.f}, S2 = {0.f, 0.f};
    #pragma unroll
    for (int n = 1; n <= 10; n++) {
        float c  = 1.f / (float)n;               // folds to a literal
        float qc = qxi * c;
        cplx nT0 = { -qc * T2.im, qc * T2.re };
        cplx nT1 = { c * fmaf(px, T2.re, T0.re), c * fmaf(px, T2.im, T0.im) };
        cplx nT2 = { c * T1.re, c * T1.im };
        T0 = nT0; T1 = nT1; T2 = nT2;
        S0 = cadd(S0, T0); S1 = cadd(S1, T1); S2 = cadd(S2, T2);
    }

    const float q2 = 2.f * qxi;
    for (int k = 0; k < sc; k++) {
        cplx f0 = S0, f1 = S1, f2 = S2;
        cplx f12 = cmul(f1, f2);
        cplx f01 = cmul(f0, f1);
        cplx f02 = cmul(f0, f2);
        float f00re = fmaf(f0.re, f0.re, -(f0.im * f0.im)), f00im = 2.f * f0.re * f0.im;
        float f11re = fmaf(f1.re, f1.re, -(f1.im * f1.im)), f11im = 2.f * f1.re * f1.im;
        float f22re = fmaf(f2.re, f2.re, -(f2.im * f2.im)), f22im = 2.f * f2.re * f2.im;
        S0.re = fmaf(-q2, f12.im, f00re);
        S0.im = fmaf( q2, f12.re, f00im);
        S1.re = fmaf(-qxi, f22im, 2.f * fmaf(px, f12.re, f01.re));
        S1.im = fmaf( qxi, f22re, 2.f * fmaf(px, f12.im, f01.im));
        S2.re = fmaf(px, f22re, fmaf(2.f, f02.re, f11re));
        S2.im = fmaf(px, f22im, fmaf(2.f, f02.im, f11im));
    }
    G3 g;
    g.g0 = S0;
    g.g1 = { S1.re * inv,  S1.im * inv  };
    g.g2 = { S2.re * inv2, S2.im * inv2 };
    return g;
}

__device__ __forceinline__ C3 ecol(Edof E, C3 m)
{
    C3 v;
    v.c0.re = fmaf(-E.ed0, m.c0.im, fmaf(E.er01, m.c1.re, fmaf(-E.ei01, m.c1.im, fmaf(E.er02, m.c2.re, -(E.ei02 * m.c2.im)))));
    v.c0.im = fmaf( E.ed0, m.c0.re, fmaf(E.er01, m.c1.im, fmaf( E.ei01, m.c1.re, fmaf(E.er02, m.c2.im,  (E.ei02 * m.c2.re)))));
    v.c1.re = fmaf(-E.er01, m.c0.re, fmaf(-E.ei01, m.c0.im, fmaf(-E.ed1, m.c1.im, fmaf(E.er12, m.c2.re, -(E.ei12 * m.c2.im)))));
    v.c1.im = fmaf(-E.er01, m.c0.im, fmaf( E.ei01, m.c0.re, fmaf( E.ed1, m.c1.re, fmaf(E.er12, m.c2.im,  (E.ei12 * m.c2.re)))));
    v.c2.re = fmaf(-E.er02, m.c0.re, fmaf(-E.ei02, m.c0.im, fmaf(-E.er12, m.c1.re, fmaf(-E.ei12, m.c1.im, -(E.ed2 * m.c2.im)))));
    v.c2.im = fmaf(-E.er02, m.c0.im, fmaf( E.ei02, m.c0.re, fmaf(-E.er12, m.c1.im, fmaf( E.ei12, m.c1.re,  (E.ed2 * m.c2.re)))));
    return v;
}

__device__ __forceinline__ float ocomb(G3 g, cplx m, cplx v, cplx z) {
    return fmaf(g.g0.re, m.re, fmaf(-g.g0.im, m.im, fmaf(g.g1.re, v.re, fmaf(-g.g1.im, v.im,
           fmaf(g.g2.re, z.re, -(g.g2.im * z.im))))));
}

// one full mu-phase. U loads issue FIRST (their ~700 cy latency hides under
// expm's ~300-op chain); all values by-value, nothing addressable.
__device__ __forceinline__ void phase(Acc9 acc,
                                      const float* __restrict__ U_re,
                                      const float* __restrict__ U_im,
                                      float* __restrict__ out, size_t ub)
{
    f3 ua = ld3(U_re + ub), ubv = ld3(U_re + ub + 3), uc = ld3(U_re + ub + 6);
    f3 va = ld3(U_im + ub), vb  = ld3(U_im + ub + 3), vc = ld3(U_im + ub + 6);

    Edof E = make_edof(acc);
    G3 g = expm_coeffs(E);

    float o0,o1,o2,o3,o4,o5,o6,o7,o8;
    {   // column 0: U elements 0,3,6
        C3 m = { cplx{ua.x, va.x}, cplx{ubv.x, vb.x}, cplx{uc.x, vc.x} };
        C3 v = ecol(E, m);
        C3 z = ecol(E, v);
        o0 = ocomb(g, m.c0, v.c0, z.c0);
        o3 = ocomb(g, m.c1, v.c1, z.c1);
        o6 = ocomb(g, m.c2, v.c2, z.c2);
    }
    {   // column 1: U elements 1,4,7
        C3 m = { cplx{ua.y, va.y}, cplx{ubv.y, vb.y}, cplx{uc.y, vc.y} };
        C3 v = ecol(E, m);
        C3 z = ecol(E, v);
        o1 = ocomb(g, m.c0, v.c0, z.c0);
        o4 = ocomb(g, m.c1, v.c1, z.c1);
        o7 = ocomb(g, m.c2, v.c2, z.c2);
    }
    {   // column 2: U elements 2,5,8
        C3 m = { cplx{ua.z, va.z}, cplx{ubv.z, vb.z}, cplx{uc.z, vc.z} };
        C3 v = ecol(E, m);
        C3 z = ecol(E, v);
        o2 = ocomb(g, m.c0, v.c0, z.c0);
        o5 = ocomb(g, m.c1, v.c1, z.c1);
        o8 = ocomb(g, m.c2, v.c2, z.c2);
    }
    float* ob = out + ub;
    *(f3*)(ob)     = { o0, o1, o2 };
    *(f3*)(ob + 3) = { o3, o4, o5 };
    *(f3*)(ob + 6) = { o6, o7, o8 };
}

// TWO MU PER LANE — the midpoint the data demands. R4/R8 (1 mu/lane, 32
// waves/CU of work, 4x duplicated W stream): 42-45 us. R11 (4 mu/lane, 8
// waves/CU, lean stream, clean 100-VGPR codegen): 54 us -- the dedup cut
// memory work 2.6x but cut latency-hiding 4x; net LOSS. => latency/issue-
// bound, controlled by (waves in flight) x (per-wave VMEM instructions).
// Here: lane owns site's W once (40 loads) but only mu {half, half+2}
// (half = gid&1): 4096 waves = 16 waves/CU, W duplication 2x, ~58 VMEM/lane.
// ahw weights selected from SGPRs by one cndmask per feature.
//
// waves_per_eu NOTE (measured): allocator NEVER exceeds 64 VGPR unless told
// occupancy is capped (R11: waves_per_eu(2,2) -> 100 VGPR, zero scratch).
// Here waves_per_eu(4,4) = 128-reg budget; working set ~90-110 fits.
__global__
__attribute__((amdgpu_flat_work_group_size(256, 256)))
__attribute__((amdgpu_waves_per_eu(4, 4)))
void lge_exp_kernel(
    const float* __restrict__ U_re, const float* __restrict__ U_im,
    const float* __restrict__ W_re, const float* __restrict__ W_im,
    const float* __restrict__ ahw,  float* __restrict__ out)
{
    const int gid  = blockIdx.x * 256 + threadIdx.x;   // 0..262143
    const int site = gid >> 1;         // 2 lanes per site
    const int half = gid & 1;          // 0 -> mu {0,2}; 1 -> mu {1,3}
    const size_t sb = (size_t)site * 9;

    Acc9 A0 = {0,0,0,0,0,0,0,0,0};     // mu = half
    Acc9 A1 = {0,0,0,0,0,0,0,0,0};     // mu = half + 2

    #pragma unroll
    for (int f = 0; f < 8; f++) {
        const float* pr = W_re + (size_t)f * PL + sb;
        const float* pi = W_im + (size_t)f * PL + sb;
        f3 q  = ld3(pr + 1);           // w1 w2 w3
        f3 s  = ld3(pr + 5);           // w5 w6 w7
        f3 ia = ld3(pi), ib = ld3(pi + 3), ic = ld3(pi + 6);

        // pre-reduce this feature to the 9 floats E consumes (named scalars)
        const float p0 = q.x - q.z;          // re01
        const float p1 = q.y - s.y;          // re02
        const float p2 = s.x - s.z;          // re12
        const float p3 = ia.y + ib.x;        // si01 = wi1 + wi3
        const float p4 = ia.z + ic.x;        // si02 = wi2 + wi6
        const float p5 = ib.z + ic.y;        // si12 = wi5 + wi7
        const float p6 = ia.x, p7 = ib.y, p8 = ic.z;   // wi0, wi4, wi8

        // ahw rows are uniform (s_load); per-lane mu-pair selection is one
        // cndmask per weight. f is compile-time after unroll.
        const float wA = half ? ahw[1 * 8 + f] : ahw[0 * 8 + f];   // mu = half
        const float wB = half ? ahw[3 * 8 + f] : ahw[2 * 8 + f];   // mu = half+2

        A0.r01=fmaf(wA,p0,A0.r01); A0.r02=fmaf(wA,p1,A0.r02); A0.r12=fmaf(wA,p2,A0.r12);
        A0.i01=fmaf(wA,p3,A0.i01); A0.i02=fmaf(wA,p4,A0.i02); A0.i12=fmaf(wA,p5,A0.i12);
        A0.d0 =fmaf(wA,p6,A0.d0);  A0.d4 =fmaf(wA,p7,A0.d4);  A0.d8 =fmaf(wA,p8,A0.d8);

        A1.r01=fmaf(wB,p0,A1.r01); A1.r02=fmaf(wB,p1,A1.r02); A1.r12=fmaf(wB,p2,A1.r12);
        A1.i01=fmaf(wB,p3,A1.i01); A1.i02=fmaf(wB,p4,A1.i02); A1.i12=fmaf(wB,p5,A1.i12);
        A1.d0 =fmaf(wB,p6,A1.d0);  A1.d4 =fmaf(wB,p7,A1.d4);  A1.d8 =fmaf(wB,p8,A1.d8);
    }

    // two phases; sched_barrier(0) stops cross-phase load hoisting (R10)
    phase(A0, U_re, U_im, out, ((size_t)half * NSITES + site) * 9);
    __builtin_amdgcn_sched_barrier(0);
    phase(A1, U_re, U_im, out, ((size_t)(half + 2) * NSITES + site) * 9);
}

extern "C" void kernel_launch(void* const* d_in, const int* in_sizes, int n_in,
                              void* d_out, int out_size, void* d_ws, size_t ws_size,
                              hipStream_t stream) {
    const float* U_re = (const float*)d_in[0];
    const float* U_im = (const float*)d_in[1];
    const float* W_re = (const float*)d_in[2];
    const float* W_im = (const float*)d_in[3];
    const float* ahw  = (const float*)d_in[4];
    float* out = (float*)d_out;
    // two mu per lane: 262144 lanes = 1024 blocks x 256 = 16 waves/CU
    lge_exp_kernel<<<dim3(NSITES * 2 / 256), dim3(256), 0, stream>>>(
        U_re, U_im, W_re, W_im, ahw, out);
}

// Round 13
// 145.653 us; speedup vs baseline: 1.0639x; 1.0639x over previous
//
#include <hip/hip_runtime.h>
#include <math.h>

#define NSITES 131072      // 32*16*16*16
#define PL     (NSITES * 9)   // floats per feature plane

struct cplx { float re, im; };

__device__ __forceinline__ cplx cadd(cplx a, cplx b) { return {a.re + b.re, a.im + b.im}; }
__device__ __forceinline__ cplx cmul(cplx a, cplx b) {
    return { fmaf(a.re, b.re, -(a.im * b.im)), fmaf(a.re, b.im, a.im * b.re) };
}

// 12-byte vector load (global_load_dwordx3); rows are 36 B so only 4B-aligned
struct __attribute__((aligned(4))) f3 { float x, y, z; };
__device__ __forceinline__ f3 ld3(const float* __restrict__ p) { return *(const f3*)p; }

// One feature's W data: 5 independent dwordx3 loads, returned BY VALUE.
struct F5 { f3 q, s, ia, ib, ic; };
__device__ __forceinline__ F5 ldw(const float* __restrict__ pr,
                                  const float* __restrict__ pi) {
    F5 r;
    r.q  = ld3(pr + 1);    // w_re 1,2,3
    r.s  = ld3(pr + 5);    // w_re 5,6,7
    r.ia = ld3(pi);        // w_im 0,1,2
    r.ib = ld3(pi + 3);    // w_im 3,4,5
    r.ic = ld3(pi + 6);    // w_im 6,7,8
    return r;
}

// Named-field structs, everything BY VALUE (R9 pointer-array and R10
// by-reference both stack-demoted -> 27-45 MB scratch; R11 by-value = clean).
struct Acc9 { float r01, r02, r12, i01, i02, i12, d0, d4, d8; };
struct Edof { float er01, er02, er12, ei01, ei02, ei12, ed0, ed1, ed2; };
struct G3   { cplx g0, g1, g2; };
struct C3   { cplx c0, c1, c2; };

// accumulate one feature (pre-reduction fused) into A with weight wf
#define ACCF(W, wf) do { \
    const float p0 = W.q.x - W.q.z,  p1 = W.q.y - W.s.y,  p2 = W.s.x - W.s.z; \
    const float p3 = W.ia.y + W.ib.x, p4 = W.ia.z + W.ic.x, p5 = W.ib.z + W.ic.y; \
    A.r01 = fmaf(wf, p0, A.r01); A.r02 = fmaf(wf, p1, A.r02); A.r12 = fmaf(wf, p2, A.r12); \
    A.i01 = fmaf(wf, p3, A.i01); A.i02 = fmaf(wf, p4, A.i02); A.i12 = fmaf(wf, p5, A.i12); \
    A.d0  = fmaf(wf, W.ia.x, A.d0); A.d4 = fmaf(wf, W.ib.y, A.d4); A.d8 = fmaf(wf, W.ic.z, A.d8); \
} while (0)

__device__ __forceinline__ Edof make_edof(Acc9 a) {
    Edof E;
    E.er01 = a.r01; E.er02 = a.r02; E.er12 = a.r12;
    E.ei01 = a.i01; E.ei02 = a.i02; E.ei12 = a.i12;
    float t3 = (a.d0 + a.d4 + a.d8) * (2.f / 3.f);
    E.ed0 = fmaf(2.f, a.d0, -t3);
    E.ed1 = fmaf(2.f, a.d4, -t3);
    E.ed2 = fmaf(2.f, a.d8, -t3);     // == -ed0-ed1
    return E;
}

// exp(E) = g0 I + g1 E + g2 E^2 via Cayley-Hamilton (p real, q imaginary),
// scaling from exponent bits of ||E||_F^2, Taylor(10) + repeated squaring.
__device__ __forceinline__ G3 expm_coeffs(Edof E)
{
    float r2 = fmaf(E.er01, E.er01, fmaf(E.er02, E.er02, fmaf(E.er12, E.er12,
               fmaf(E.ei01, E.ei01, fmaf(E.ei02, E.ei02, E.ei12 * E.ei12)))));
    r2 = fmaf(2.f, r2, fmaf(E.ed0, E.ed0, fmaf(E.ed1, E.ed1, E.ed2 * E.ed2)));

    const float n01 = fmaf(E.ei01, E.ei01, E.er01 * E.er01);
    const float n02 = fmaf(E.ei02, E.ei02, E.er02 * E.er02);
    const float n12 = fmaf(E.ei12, E.ei12, E.er12 * E.er12);
    const float zre = fmaf(E.ei01, E.ei12, -(E.er01 * E.er12));
    const float zim = -fmaf(E.ei01, E.er12, E.er01 * E.ei12);
    const float detH = E.ed0 * E.ed1 * E.ed2
                     + 2.f * fmaf(zre, E.ei02, -(zim * E.er02))
                     - fmaf(E.ed0, n12, fmaf(E.ed1, n02, E.ed2 * n01));

    int e; (void)frexpf(r2, &e);                 // r2 = m*2^e, m in [0.5,1)
    int sc = (e <= -2) ? 0 : min(1 + ((e + 1) >> 1), 40);
    const float inv  = __int_as_float((127 - sc) << 23);   // 2^-sc
    const float inv2 = inv * inv;
    const float px   = -0.5f * r2 * inv2;        // p of scaled X (real)
    const float qxi  = -detH * (inv2 * inv);     // q of scaled X = i*qxi

    cplx T0 = {1.f, 0.f}, T1 = {0.f, 0.f}, T2 = {0.f, 0.f};
    cplx S0 = {1.f, 0.f}, S1 = {0.f, 0.f}, S2 = {0.f, 0.f};
    #pragma unroll
    for (int n = 1; n <= 10; n++) {
        float c  = 1.f / (float)n;               // folds to a literal
        float qc = qxi * c;
        cplx nT0 = { -qc * T2.im, qc * T2.re };
        cplx nT1 = { c * fmaf(px, T2.re, T0.re), c * fmaf(px, T2.im, T0.im) };
        cplx nT2 = { c * T1.re, c * T1.im };
        T0 = nT0; T1 = nT1; T2 = nT2;
        S0 = cadd(S0, T0); S1 = cadd(S1, T1); S2 = cadd(S2, T2);
    }

    const float q2 = 2.f * qxi;
    for (int k = 0; k < sc; k++) {
        cplx f0 = S0, f1 = S1, f2 = S2;
        cplx f12 = cmul(f1, f2);
        cplx f01 = cmul(f0, f1);
        cplx f02 = cmul(f0, f2);
        float f00re = fmaf(f0.re, f0.re, -(f0.im * f0.im)), f00im = 2.f * f0.re * f0.im;
        float f11re = fmaf(f1.re, f1.re, -(f1.im * f1.im)), f11im = 2.f * f1.re * f1.im;
        float f22re = fmaf(f2.re, f2.re, -(f2.im * f2.im)), f22im = 2.f * f2.re * f2.im;
        S0.re = fmaf(-q2, f12.im, f00re);
        S0.im = fmaf( q2, f12.re, f00im);
        S1.re = fmaf(-qxi, f22im, 2.f * fmaf(px, f12.re, f01.re));
        S1.im = fmaf( qxi, f22re, 2.f * fmaf(px, f12.im, f01.im));
        S2.re = fmaf(px, f22re, fmaf(2.f, f02.re, f11re));
        S2.im = fmaf(px, f22im, fmaf(2.f, f02.im, f11im));
    }
    G3 g;
    g.g0 = S0;
    g.g1 = { S1.re * inv,  S1.im * inv  };
    g.g2 = { S2.re * inv2, S2.im * inv2 };
    return g;
}

__device__ __forceinline__ C3 ecol(Edof E, C3 m)
{
    C3 v;
    v.c0.re = fmaf(-E.ed0, m.c0.im, fmaf(E.er01, m.c1.re, fmaf(-E.ei01, m.c1.im, fmaf(E.er02, m.c2.re, -(E.ei02 * m.c2.im)))));
    v.c0.im = fmaf( E.ed0, m.c0.re, fmaf(E.er01, m.c1.im, fmaf( E.ei01, m.c1.re, fmaf(E.er02, m.c2.im,  (E.ei02 * m.c2.re)))));
    v.c1.re = fmaf(-E.er01, m.c0.re, fmaf(-E.ei01, m.c0.im, fmaf(-E.ed1, m.c1.im, fmaf(E.er12, m.c2.re, -(E.ei12 * m.c2.im)))));
    v.c1.im = fmaf(-E.er01, m.c0.im, fmaf( E.ei01, m.c0.re, fmaf( E.ed1, m.c1.re, fmaf(E.er12, m.c2.im,  (E.ei12 * m.c2.re)))));
    v.c2.re = fmaf(-E.er02, m.c0.re, fmaf(-E.ei02, m.c0.im, fmaf(-E.er12, m.c1.re, fmaf(-E.ei12, m.c1.im, -(E.ed2 * m.c2.im)))));
    v.c2.im = fmaf(-E.er02, m.c0.im, fmaf( E.ei02, m.c0.re, fmaf(-E.er12, m.c1.im, fmaf( E.ei12, m.c1.re,  (E.ed2 * m.c2.re)))));
    return v;
}

__device__ __forceinline__ float ocomb(G3 g, cplx m, cplx v, cplx z) {
    return fmaf(g.g0.re, m.re, fmaf(-g.g0.im, m.im, fmaf(g.g1.re, v.re, fmaf(-g.g1.im, v.im,
           fmaf(g.g2.re, z.re, -(g.g2.im * z.im))))));
}

// ONE (site,mu) PER LANE (R4's proven grid/coalescing: mu-quad lanes share W
// addresses -> TA-merged) + BATCHED LOAD ISSUE + 256-REG BUDGET.
//
// Why: clean-codegen map so far -- {32 waves/CU, 64 VGPR, ~5 loads in
// flight/wave} = 42-45 us (R4/R8); {8 waves/CU, 100 VGPR} = 54 us (R11, loads
// ~700 ns/op = fully serialized). Latency-bound: the untested cell is MANY
// waves x MANY outstanding loads. Here: U's 6 loads at top, then W in two
// batches of 4 features x 5 ld3 = 20 independent loads issued before any use
// (60 VGPR landing zone). Per-wave outstanding ~5 -> ~26.
//
// ALLOCATOR LAW (R0-R12, 13 experiments): budget >= 2x working set -> clean;
// budget ~ working set -> pressure-mode spill (R1: 155 MB, R2: 48 MB, R12:
// 43 MB scratch). Only min-2-waves configs ever exceeded 64 VGPR cleanly
// (R11: 100 VGPR, zero scratch). launch_bounds(256,2) = 256-reg budget >>
// ~110 working set; at <=128 VGPR runtime still gets 4 waves/SIMD.
__global__ __launch_bounds__(256, 2) void lge_exp_kernel(
    const float* __restrict__ U_re, const float* __restrict__ U_im,
    const float* __restrict__ W_re, const float* __restrict__ W_im,
    const float* __restrict__ ahw,  float* __restrict__ out)
{
    const int gid   = blockIdx.x * 256 + threadIdx.x;
    const int gsite = gid >> 2;        // 0..131071 (4-lane group shares a site)
    const int mu    = gid & 3;
    const size_t sb = (size_t)gsite * 9;

    // ---- U loads first: 6 ld3 in flight under everything up to the epilogue
    const size_t ub = ((size_t)mu * NSITES + gsite) * 9;
    f3 ua = ld3(U_re + ub), ubv = ld3(U_re + ub + 3), uc = ld3(U_re + ub + 6);
    f3 va = ld3(U_im + ub), vb  = ld3(U_im + ub + 3), vc = ld3(U_im + ub + 6);

    // ahw row for this mu: two aligned float4 loads
    const float4* ahw4 = (const float4*)ahw;
    float4 wlo = ahw4[mu * 2], whi = ahw4[mu * 2 + 1];

    Acc9 A = {0,0,0,0,0,0,0,0,0};

    // ---- batch 0: features 0-3, 20 independent ld3 issued back-to-back ----
    {
        F5 w0 = ldw(W_re + (size_t)0 * PL + sb, W_im + (size_t)0 * PL + sb);
        F5 w1 = ldw(W_re + (size_t)1 * PL + sb, W_im + (size_t)1 * PL + sb);
        F5 w2 = ldw(W_re + (size_t)2 * PL + sb, W_im + (size_t)2 * PL + sb);
        F5 w3 = ldw(W_re + (size_t)3 * PL + sb, W_im + (size_t)3 * PL + sb);
        ACCF(w0, wlo.x); ACCF(w1, wlo.y); ACCF(w2, wlo.z); ACCF(w3, wlo.w);
    }
    // ---- batch 1: features 4-7 (same 60-reg landing zone reused) ----
    {
        F5 w4 = ldw(W_re + (size_t)4 * PL + sb, W_im + (size_t)4 * PL + sb);
        F5 w5 = ldw(W_re + (size_t)5 * PL + sb, W_im + (size_t)5 * PL + sb);
        F5 w6 = ldw(W_re + (size_t)6 * PL + sb, W_im + (size_t)6 * PL + sb);
        F5 w7 = ldw(W_re + (size_t)7 * PL + sb, W_im + (size_t)7 * PL + sb);
        ACCF(w4, whi.x); ACCF(w5, whi.y); ACCF(w6, whi.z); ACCF(w7, whi.w);
    }

    const Edof E = make_edof(A);
    const G3 g = expm_coeffs(E);

    float o0,o1,o2,o3,o4,o5,o6,o7,o8;
    {   // column 0: U elements 0,3,6
        C3 m = { cplx{ua.x, va.x}, cplx{ubv.x, vb.x}, cplx{uc.x, vc.x} };
        C3 v = ecol(E, m);
        C3 z = ecol(E, v);
        o0 = ocomb(g, m.c0, v.c0, z.c0);
        o3 = ocomb(g, m.c1, v.c1, z.c1);
        o6 = ocomb(g, m.c2, v.c2, z.c2);
    }
    {   // column 1: U elements 1,4,7
        C3 m = { cplx{ua.y, va.y}, cplx{ubv.y, vb.y}, cplx{uc.y, vc.y} };
        C3 v = ecol(E, m);
        C3 z = ecol(E, v);
        o1 = ocomb(g, m.c0, v.c0, z.c0);
        o4 = ocomb(g, m.c1, v.c1, z.c1);
        o7 = ocomb(g, m.c2, v.c2, z.c2);
    }
    {   // column 2: U elements 2,5,8
        C3 m = { cplx{ua.z, va.z}, cplx{ubv.z, vb.z}, cplx{uc.z, vc.z} };
        C3 v = ecol(E, m);
        C3 z = ecol(E, v);
        o2 = ocomb(g, m.c0, v.c0, z.c0);
        o5 = ocomb(g, m.c1, v.c1, z.c1);
        o8 = ocomb(g, m.c2, v.c2, z.c2);
    }
    float* ob = out + ub;
    *(f3*)(ob)     = { o0, o1, o2 };
    *(f3*)(ob + 3) = { o3, o4, o5 };
    *(f3*)(ob + 6) = { o6, o7, o8 };
}

extern "C" void kernel_launch(void* const* d_in, const int* in_sizes, int n_in,
                              void* d_out, int out_size, void* d_ws, size_t ws_size,
                              hipStream_t stream) {
    const float* U_re = (const float*)d_in[0];
    const float* U_im = (const float*)d_in[1];
    const float* W_re = (const float*)d_in[2];
    const float* W_im = (const float*)d_in[3];
    const float* ahw  = (const float*)d_in[4];
    float* out = (float*)d_out;
    // one lane per (site, mu): 524288 lanes = 2048 blocks x 256
    lge_exp_kernel<<<dim3(NSITES * 4 / 256), dim3(256), 0, stream>>>(
        U_re, U_im, W_re, W_im, ahw, out);
}